// Round 1
// baseline (995.211 us; speedup 1.0000x reference)
//
#include <hip/hip_runtime.h>

// TV denoiser (Chambolle-Pock, deepinv-style), 40 fixed iterations.
// x update needs u2 at (i-1,j),(i,j-1),(i,j); u update needs x at (i,j),(i+1,j),(i,j+1).
// One kernel per iteration: compute x on a 33x33 extended LDS region so the
// u-update's forward differences of (2x - x2) stay block-local.

#define Hh 512
#define Ww 512
#define Bb 8
#define TILE 32
#define EXT 33   // TILE+1
#define HLO 34   // TILE+2

__global__ __launch_bounds__(256)
void tv_iter(const float* __restrict__ x2_in,
             const float* __restrict__ u0_in,
             const float* __restrict__ u1_in,
             const float* __restrict__ y_in,
             float* __restrict__ x2_out,
             float* __restrict__ u0_out,
             float* __restrict__ u1_out)
{
    constexpr float TAU = 0.01f;
    constexpr float RHO = 1.99f;
    constexpr float SIGMA = 12.5f;      // 1/TAU/8
    constexpr float INV_THS = 10.0f;    // 1/0.1
    constexpr float INV_1PT = 1.0f / 1.01f;

    __shared__ float su0[HLO][HLO];
    __shared__ float su1[HLO][HLO];
    __shared__ float sx2[EXT][EXT];
    __shared__ float sy [EXT][EXT];
    __shared__ float sx [EXT][EXT];

    const int b  = blockIdx.z;
    const int r0 = blockIdx.y * TILE;
    const int c0 = blockIdx.x * TILE;
    const int tid = threadIdx.x;

    const size_t plane = (size_t)b * Hh * Ww;
    const float* xb  = x2_in + plane;
    const float* u0b = u0_in + plane;
    const float* u1b = u1_in + plane;
    const float* yb  = y_in  + plane;

    // ---- stage u2 with halo 1 on all sides (OOB -> 0, matches boundary conditions)
    for (int l = tid; l < HLO * HLO; l += 256) {
        int lr = l / HLO, lc = l - lr * HLO;
        int gr = r0 - 1 + lr, gc = c0 - 1 + lc;
        bool ok = (gr >= 0) & (gr < Hh) & (gc >= 0) & (gc < Ww);
        int gi = gr * Ww + gc;
        su0[lr][lc] = ok ? u0b[gi] : 0.0f;
        su1[lr][lc] = ok ? u1b[gi] : 0.0f;
    }
    // ---- stage x2, y on the extended (TILE+1)^2 region (OOB -> 0; those x values
    //      are only consumed through predicated dh/dw so garbage never propagates)
    for (int l = tid; l < EXT * EXT; l += 256) {
        int lr = l / EXT, lc = l - lr * EXT;
        int gr = r0 + lr, gc = c0 + lc;
        bool ok = (gr < Hh) & (gc < Ww);
        int gi = gr * Ww + gc;
        sx2[lr][lc] = ok ? xb[gi] : 0.0f;
        sy [lr][lc] = ok ? yb[gi] : 0.0f;
    }
    __syncthreads();

    // ---- x = (x2 - TAU*adj(u2) + TAU*y) / (1+TAU) on extended region
    for (int l = tid; l < EXT * EXT; l += 256) {
        int er = l / EXT, ec = l - er * EXT;
        // adjoint at global (r0+er, c0+ec); su* index (+1,+1) offset.
        float adj = su0[er][ec + 1] - su0[er + 1][ec + 1]
                  + su1[er + 1][ec] - su1[er + 1][ec + 1];
        sx[er][ec] = (sx2[er][ec] - TAU * adj + TAU * sy[er][ec]) * INV_1PT;
    }
    __syncthreads();

    // ---- u update + relaxation, 4 output rows per thread
    const int tx = tid & 31;
    const int ty = tid >> 5;
    for (int rr = 0; rr < TILE; rr += 8) {
        int orow = ty + rr, ocol = tx;
        int gi = r0 + orow, gj = c0 + ocol;
        float x2v = sx2[orow][ocol];
        float xv  = sx [orow][ocol];
        float t00 = 2.0f * xv - x2v;
        float dh = (gi < Hh - 1)
                 ? (2.0f * sx[orow + 1][ocol] - sx2[orow + 1][ocol]) - t00 : 0.0f;
        float dw = (gj < Ww - 1)
                 ? (2.0f * sx[orow][ocol + 1] - sx2[orow][ocol + 1]) - t00 : 0.0f;
        float u0v = su0[orow + 1][ocol + 1];
        float u1v = su1[orow + 1][ocol + 1];
        float v0 = fmaf(SIGMA, dh, u0v);
        float v1 = fmaf(SIGMA, dw, u1v);
        float mag = sqrtf(v0 * v0 + v1 * v1);
        float sc = fmaxf(mag * INV_THS, 1.0f);
        float inv = 1.0f / sc;
        float un0 = v0 * inv;
        float un1 = v1 * inv;
        size_t o = plane + (size_t)gi * Ww + gj;
        x2_out[o] = x2v + RHO * (xv - x2v);
        u0_out[o] = u0v + RHO * (un0 - u0v);
        u1_out[o] = u1v + RHO * (un1 - u1v);
    }
}

extern "C" void kernel_launch(void* const* d_in, const int* in_sizes, int n_in,
                              void* d_out, int out_size, void* d_ws, size_t ws_size,
                              hipStream_t stream)
{
    const float* y = (const float*)d_in[0];
    float* out = (float*)d_out;
    const size_t NP = (size_t)Bb * Hh * Ww;   // 2M elements per plane-set

    float* ws = (float*)d_ws;
    float* u0_a  = ws;            // 8 MB
    float* u1_a  = ws + NP;       // 8 MB
    float* u0_b  = ws + 2 * NP;
    float* u1_b  = ws + 3 * NP;
    float* x2_ws = ws + 4 * NP;   // even-iteration x2 target
    // total ws use: 5*NP*4 = 40 MB

    // u2 starts at zero (harness poisons ws with 0xAA every call)
    hipMemsetAsync(u0_a, 0, 2 * NP * sizeof(float), stream);

    dim3 grid(Ww / TILE, Hh / TILE, Bb);

    const float* x2r = y;      // x2_0 = y
    const float* u0r = u0_a;
    const float* u1r = u1_a;
    for (int it = 0; it < 40; ++it) {
        float* x2w = (it & 1) ? out : x2_ws;   // iter 39 (odd) lands in d_out
        float* u0w = (it & 1) ? u0_a : u0_b;
        float* u1w = (it & 1) ? u1_a : u1_b;
        tv_iter<<<grid, 256, 0, stream>>>(x2r, u0r, u1r, y, x2w, u0w, u1w);
        x2r = x2w; u0r = u0w; u1r = u1w;
    }
}

// Round 3
// 508.969 us; speedup vs baseline: 1.9553x; 1.9553x over previous
//
#include <hip/hip_runtime.h>

// TV denoiser (Chambolle-Pock), 40 iterations = 10 launches x 4 fused steps.
// Temporal blocking: dependency cone grows 1 px/side/step, so a 32x32 output
// tile needs a 40x40 staged region for 4 fused steps. All 4 steps run in LDS.
//
// Phase 1 stores w = 2x - x2 (not x): phase 2's forward differences then read
// only the w array, so the in-place updates of su0/su1/sx2 (each thread writes
// only its own element) are race-free with one barrier between phases.
//
// Boundary handling: OOB staging = 0 emulates the adjoint's boundary terms.
// CRITICAL (round-2 bug): phase 2 must NOT update OOB cells — otherwise
// u(row -1) drifts nonzero (dh = w(row0) - w(OOB)) and re-feeds image row 0
// through the adjoint at later fused steps (absmax 0.109 > 0.1006 failure).
// The in-image predicate keeps OOB state at exactly 0 across all fused steps,
// matching the global semantics (u outside the image == 0 forever).

#define Hh 512
#define Ww 512
#define Bb 8
#define TS 32
#define KF 4
#define S  40          // TS + 2*KF
#define SS (S*S)       // 1600

__global__ __launch_bounds__(256)
void tv_fused(const float* __restrict__ x2_in,
              const float* __restrict__ u0_in,
              const float* __restrict__ u1_in,
              const float* __restrict__ y_in,
              float* __restrict__ x2_out,
              float* __restrict__ u0_out,
              float* __restrict__ u1_out)
{
    constexpr float TAU = 0.01f;
    constexpr float RHO = 1.99f;
    constexpr float SIGMA = 12.5f;       // 1/TAU/8
    constexpr float INV_THS = 10.0f;     // 1/0.1
    constexpr float INV_1PT = 1.0f / 1.01f;

    __shared__ float sx2[SS], su0[SS], su1[SS], sy[SS], sw[SS];

    const int b   = blockIdx.z;
    const int r0  = blockIdx.y * TS;
    const int c0  = blockIdx.x * TS;
    const int tid = threadIdx.x;
    const size_t plane = (size_t)b * (Hh * Ww);

    // ---- stage x2, u0, u1, y on the 40x40 region (OOB -> 0)
    for (int l = tid; l < SS; l += 256) {
        int lr = l / S, lc = l - lr * S;
        int gr = r0 - KF + lr, gc = c0 - KF + lc;
        bool ok = (gr >= 0) & (gr < Hh) & (gc >= 0) & (gc < Ww);
        float a = 0.f, b0 = 0.f, b1 = 0.f, c = 0.f;
        if (ok) {
            size_t gi = plane + (size_t)gr * Ww + gc;
            a  = x2_in[gi];
            b0 = u0_in[gi];
            b1 = u1_in[gi];
            c  = y_in [gi];
        }
        sx2[l] = a; su0[l] = b0; su1[l] = b1; sy[l] = c;
    }
    __syncthreads();

    #pragma unroll
    for (int t = 0; t < KF; ++t) {
        // ---- phase 1: w = 2x - x2 on [t+1, S-t)^2
        for (int l = tid; l < SS; l += 256) {
            int lr = l / S, lc = l - lr * S;
            if (lr > t && lr < S - t && lc > t && lc < S - t) {
                float adj = su0[l - S] - su0[l] + su1[l - 1] - su1[l];
                float tmp = fmaf(TAU, sy[l] - adj, sx2[l]);   // x*(1+TAU)
                sw[l] = fmaf(2.0f * INV_1PT, tmp, -sx2[l]);   // 2x - x2
            }
        }
        __syncthreads();
        // ---- phase 2: u, x2 update in place on [t+1, S-t-1)^2, IMAGE CELLS ONLY
        for (int l = tid; l < SS; l += 256) {
            int lr = l / S, lc = l - lr * S;
            int gr = r0 - KF + lr, gc = c0 - KF + lc;
            bool in_img = (gr >= 0) & (gr < Hh) & (gc >= 0) & (gc < Ww);
            if (in_img && lr > t && lr < S - t - 1 && lc > t && lc < S - t - 1) {
                float wv = sw[l];
                float dh = (gr < Hh - 1) ? sw[l + S] - wv : 0.f;
                float dw = (gc < Ww - 1) ? sw[l + 1] - wv : 0.f;
                float u0v = su0[l], u1v = su1[l];
                float v0 = fmaf(SIGMA, dh, u0v);
                float v1 = fmaf(SIGMA, dw, u1v);
                float mag = sqrtf(fmaf(v0, v0, v1 * v1));
                float inv = 1.0f / fmaxf(mag * INV_THS, 1.0f);
                su0[l] = fmaf(RHO, v0 * inv - u0v, u0v);
                su1[l] = fmaf(RHO, v1 * inv - u1v, u1v);
                float x2v = sx2[l];
                sx2[l] = fmaf(0.5f * RHO, wv - x2v, x2v);     // x2 + RHO*(x-x2)
            }
        }
        __syncthreads();
    }

    // ---- store central 32x32: x2, u0, u1 (coalesced)
    for (int l = tid; l < TS * TS; l += 256) {
        int orr = l >> 5, oc = l & (TS - 1);
        int sidx = (KF + orr) * S + (KF + oc);
        size_t gi = plane + (size_t)(r0 + orr) * Ww + (c0 + oc);
        x2_out[gi] = sx2[sidx];
        u0_out[gi] = su0[sidx];
        u1_out[gi] = su1[sidx];
    }
}

extern "C" void kernel_launch(void* const* d_in, const int* in_sizes, int n_in,
                              void* d_out, int out_size, void* d_ws, size_t ws_size,
                              hipStream_t stream)
{
    const float* y = (const float*)d_in[0];
    float* out = (float*)d_out;
    const size_t NP = (size_t)Bb * Hh * Ww;   // 2M elements

    float* ws  = (float*)d_ws;
    float* x2A = ws;
    float* x2B = ws + NP;
    float* u0B = ws + 2 * NP;   // zeroed, read at launch 0
    float* u1B = ws + 3 * NP;   // zeroed (contiguous with u0B)
    float* u0A = ws + 4 * NP;
    float* u1A = ws + 5 * NP;
    // total ws use: 6*NP*4 = 48 MB

    hipMemsetAsync(u0B, 0, 2 * NP * sizeof(float), stream);

    dim3 grid(Ww / TS, Hh / TS, Bb);

    const float* x2r = y;       // x2_0 = y
    const float* u0r = u0B;
    const float* u1r = u1B;
    for (int i = 0; i < 10; ++i) {
        bool even = (i & 1) == 0;
        float* x2w = (i == 9) ? out : (even ? x2A : x2B);
        float* u0w = even ? u0A : u0B;
        float* u1w = even ? u1A : u1B;
        tv_fused<<<grid, 256, 0, stream>>>(x2r, u0r, u1r, y, x2w, u0w, u1w);
        x2r = x2w; u0r = u0w; u1r = u1w;
    }
}

// Round 4
// 424.119 us; speedup vs baseline: 2.3465x; 1.2001x over previous
//
#include <hip/hip_runtime.h>

// TV denoiser (Chambolle-Pock), 40 iterations = 10 launches x 4 fused steps.
// Temporal blocking on a 40x40 staged region -> central 32x32 output.
//
// Thread tid owns cells l = tid + 256k (k=0..6). Per-cell coords/flags are
// computed ONCE into registers; x2 and y are private to the owning cell so
// they live in registers too. Only u0, u1, w (shared with neighbors through
// the adjoint / forward differences) are in LDS -> 19.2 KB/block.
//
// Phase 1 (w = 2x - x2) runs on every cell with lr,lc >= 1 (t-independent
// mask; w outside the valid cone is garbage but provably never read by a
// valid phase-2 cell). Phase 2 keeps the EXACT shrinking-region + in-image
// mask: OOB cells must stay identically 0 (round-2 bug: letting them drift
// feeds error back through the adjoint -> absmax 0.109 fail).

#define Hh 512
#define Ww 512
#define Bb 8
#define TS 32
#define KF 4
#define S  40          // TS + 2*KF
#define SS (S*S)       // 1600
#define NK 7           // ceil(SS/256)

__global__ __launch_bounds__(256, 6)
void tv_fused(const float* __restrict__ x2_in,
              const float* __restrict__ u0_in,
              const float* __restrict__ u1_in,
              const float* __restrict__ y_in,
              float* __restrict__ x2_out,
              float* __restrict__ u0_out,
              float* __restrict__ u1_out)
{
    constexpr float TAU = 0.01f;
    constexpr float RHO = 1.99f;
    constexpr float SIGMA = 12.5f;       // 1/TAU/8
    constexpr float INV_THS = 10.0f;     // 1/0.1
    constexpr float INV_1PT = 1.0f / 1.01f;

    __shared__ float su0[SS], su1[SS], sw[SS];

    const int b   = blockIdx.z;
    const int r0  = blockIdx.y * TS;
    const int c0  = blockIdx.x * TS;
    const int tid = threadIdx.x;
    const size_t plane = (size_t)b * (Hh * Ww);

    // per-owned-cell state (registers)
    int   lrs[NK], lcs[NK];
    float x2r[NK], yr[NK];
    int   flg[NK];   // bit0=p1 (act && lr>=1 && lc>=1), bit1=img, bit2=eh, bit3=ew, bit4=central

    {
        int lr = tid / S, lc = tid - (tid / S) * S;
        #pragma unroll
        for (int k = 0; k < NK; ++k) {
            int l = tid + k * 256;
            bool act = (l < SS);
            lrs[k] = lr; lcs[k] = lc;
            int gr = r0 - KF + lr, gc = c0 - KF + lc;
            bool img = act & (gr >= 0) & (gr < Hh) & (gc >= 0) & (gc < Ww);
            bool eh  = gr < Hh - 1;
            bool ew  = gc < Ww - 1;
            bool p1  = act & (lr >= 1) & (lc >= 1);
            bool cen = act & (lr >= KF) & (lr < KF + TS) & (lc >= KF) & (lc < KF + TS);
            flg[k] = (p1 ? 1 : 0) | (img ? 2 : 0) | (eh ? 4 : 0) | (ew ? 8 : 0) | (cen ? 16 : 0);
            float a = 0.f, b0 = 0.f, b1 = 0.f, c = 0.f;
            if (img) {
                size_t gi = plane + (size_t)gr * Ww + gc;
                a  = x2_in[gi];
                b0 = u0_in[gi];
                b1 = u1_in[gi];
                c  = y_in [gi];
            }
            x2r[k] = a; yr[k] = c;
            if (act) { su0[l] = b0; su1[l] = b1; }
            // advance (lr,lc) by 256 cells: 256 = 6*S + 16
            lr += 6; lc += 16;
            if (lc >= S) { lc -= S; lr += 1; }
        }
    }
    __syncthreads();

    for (int t = 0; t < KF; ++t) {
        // ---- phase 1: w = 2x - x2 (t-independent mask)
        #pragma unroll
        for (int k = 0; k < NK; ++k) {
            if (flg[k] & 1) {
                int l = tid + k * 256;
                float adj = su0[l - S] - su0[l] + su1[l - 1] - su1[l];
                float tmp = fmaf(TAU, yr[k] - adj, x2r[k]);      // x*(1+TAU)
                sw[l] = fmaf(2.0f * INV_1PT, tmp, -x2r[k]);      // 2x - x2
            }
        }
        __syncthreads();
        // ---- phase 2: u, x2 update on exact region, image cells only
        #pragma unroll
        for (int k = 0; k < NK; ++k) {
            int lr = lrs[k], lc = lcs[k];
            bool m = (flg[k] & 2) && lr > t && lr < S - t - 1 && lc > t && lc < S - t - 1;
            if (m) {
                int l = tid + k * 256;
                float wv = sw[l];
                float dh = (flg[k] & 4) ? sw[l + S] - wv : 0.f;
                float dw = (flg[k] & 8) ? sw[l + 1] - wv : 0.f;
                float u0v = su0[l], u1v = su1[l];
                float v0 = fmaf(SIGMA, dh, u0v);
                float v1 = fmaf(SIGMA, dw, u1v);
                float mag = sqrtf(fmaf(v0, v0, v1 * v1));
                float inv = 1.0f / fmaxf(mag * INV_THS, 1.0f);
                su0[l] = fmaf(RHO, v0 * inv - u0v, u0v);
                su1[l] = fmaf(RHO, v1 * inv - u1v, u1v);
                x2r[k] = fmaf(0.5f * RHO, wv - x2r[k], x2r[k]);  // x2 + RHO*(x-x2)
            }
        }
        __syncthreads();
    }

    // ---- store central 32x32 from owned cells (x2 from reg, u from LDS)
    #pragma unroll
    for (int k = 0; k < NK; ++k) {
        if (flg[k] & 16) {
            int l = tid + k * 256;
            int gr = r0 + lrs[k] - KF, gc = c0 + lcs[k] - KF;
            size_t gi = plane + (size_t)gr * Ww + gc;
            x2_out[gi] = x2r[k];
            u0_out[gi] = su0[l];
            u1_out[gi] = su1[l];
        }
    }
}

extern "C" void kernel_launch(void* const* d_in, const int* in_sizes, int n_in,
                              void* d_out, int out_size, void* d_ws, size_t ws_size,
                              hipStream_t stream)
{
    const float* y = (const float*)d_in[0];
    float* out = (float*)d_out;
    const size_t NP = (size_t)Bb * Hh * Ww;   // 2M elements

    float* ws  = (float*)d_ws;
    float* x2A = ws;
    float* x2B = ws + NP;
    float* u0B = ws + 2 * NP;   // zeroed, read at launch 0
    float* u1B = ws + 3 * NP;   // zeroed (contiguous with u0B)
    float* u0A = ws + 4 * NP;
    float* u1A = ws + 5 * NP;
    // total ws use: 6*NP*4 = 48 MB

    hipMemsetAsync(u0B, 0, 2 * NP * sizeof(float), stream);

    dim3 grid(Ww / TS, Hh / TS, Bb);

    const float* x2r = y;       // x2_0 = y
    const float* u0r = u0B;
    const float* u1r = u1B;
    for (int i = 0; i < 10; ++i) {
        bool even = (i & 1) == 0;
        float* x2w = (i == 9) ? out : (even ? x2A : x2B);
        float* u0w = even ? u0A : u0B;
        float* u1w = even ? u1A : u1B;
        tv_fused<<<grid, 256, 0, stream>>>(x2r, u0r, u1r, y, x2w, u0w, u1w);
        x2r = x2w; u0r = u0w; u1r = u1w;
    }
}

// Round 5
// 354.877 us; speedup vs baseline: 2.8044x; 1.1951x over previous
//
#include <hip/hip_runtime.h>

// TV denoiser (Chambolle-Pock), 40 iterations = 5 launches x 8 fused steps.
// Temporal blocking on an 80x80 staged region -> central 64x64 output.
// Redundancy (80/64)^2 = 1.5625 equals the old (40/32)^2, so total VALU work
// is unchanged vs KF=4/TS=32 while launches and staged traffic are halved.
//
// Thread tid owns cells l = tid + 512k (k=0..12). Coords packed in registers;
// x2 and y are cell-private so they live in registers. Only u0, u1, w are in
// LDS -> 76.8 KB/block, exactly 2 blocks/CU (16 waves).
//
// Masks (induction valid for any KF):
//   phase 1 (w=2x-x2) at step t: (t, S-t) x (t, S-t), needs u valid on
//     [t, S-t)^2 which phase 2 of step t-1 maintained.
//   phase 2 at step t: (t, S-t-1) x (t, S-t-1), IMAGE CELLS ONLY — OOB cells
//     must stay exactly 0 (round-2 bug: drifting OOB u feeds back through the
//     adjoint -> absmax 0.109 fail).

#define Hh 512
#define Ww 512
#define Bb 8
#define TS 64
#define KF 8
#define S  80          // TS + 2*KF
#define SS (S*S)       // 6400
#define NT 512
#define NK 13          // ceil(SS/NT)

__global__ __launch_bounds__(NT, 4)
void tv_fused(const float* __restrict__ x2_in,
              const float* __restrict__ u0_in,
              const float* __restrict__ u1_in,
              const float* __restrict__ y_in,
              float* __restrict__ x2_out,
              float* __restrict__ u0_out,
              float* __restrict__ u1_out)
{
    constexpr float TAU = 0.01f;
    constexpr float RHO = 1.99f;
    constexpr float SIGMA = 12.5f;       // 1/TAU/8
    constexpr float INV_THS = 10.0f;     // 1/0.1
    constexpr float INV_1PT = 1.0f / 1.01f;

    __shared__ float su0[SS], su1[SS], sw[SS];

    const int b   = blockIdx.z;
    const int r0  = blockIdx.y * TS;
    const int c0  = blockIdx.x * TS;
    const int tid = threadIdx.x;
    const size_t plane = (size_t)b * (Hh * Ww);

    // per-owned-cell state (registers)
    int   crd[NK];               // lr<<8 | lc
    float x2r[NK], yr[NK];
    int   flg[NK];               // bit1=img, bit2=eh, bit3=ew, bit4=central, bit0=act

    {
        int lr = tid / S, lc = tid - (tid / S) * S;
        #pragma unroll
        for (int k = 0; k < NK; ++k) {
            int l = tid + k * NT;
            bool act = (l < SS);
            crd[k] = (lr << 8) | lc;
            int gr = r0 - KF + lr, gc = c0 - KF + lc;
            bool img = act & (gr >= 0) & (gr < Hh) & (gc >= 0) & (gc < Ww);
            bool eh  = gr < Hh - 1;
            bool ew  = gc < Ww - 1;
            bool cen = act & (lr >= KF) & (lr < KF + TS) & (lc >= KF) & (lc < KF + TS);
            flg[k] = (act ? 1 : 0) | (img ? 2 : 0) | (eh ? 4 : 0) | (ew ? 8 : 0) | (cen ? 16 : 0);
            float a = 0.f, b0 = 0.f, b1 = 0.f, c = 0.f;
            if (img) {
                size_t gi = plane + (size_t)gr * Ww + gc;
                a  = x2_in[gi];
                b0 = u0_in[gi];
                b1 = u1_in[gi];
                c  = y_in [gi];
            }
            x2r[k] = a; yr[k] = c;
            if (act) { su0[l] = b0; su1[l] = b1; }
            // advance (lr,lc) by NT cells: 512 = 6*80 + 32
            lr += 6; lc += 32;
            if (lc >= S) { lc -= S; lr += 1; }
        }
    }
    __syncthreads();

    for (int t = 0; t < KF; ++t) {
        // ---- phase 1: w = 2x - x2 on (t, S-t)^2
        #pragma unroll
        for (int k = 0; k < NK; ++k) {
            int lr = crd[k] >> 8, lc = crd[k] & 255;
            if ((flg[k] & 1) && lr > t && lr < S - t && lc > t && lc < S - t) {
                int l = tid + k * NT;
                float adj = su0[l - S] - su0[l] + su1[l - 1] - su1[l];
                float tmp = fmaf(TAU, yr[k] - adj, x2r[k]);      // x*(1+TAU)
                sw[l] = fmaf(2.0f * INV_1PT, tmp, -x2r[k]);      // 2x - x2
            }
        }
        __syncthreads();
        // ---- phase 2: u, x2 update on (t, S-t-1)^2, image cells only
        #pragma unroll
        for (int k = 0; k < NK; ++k) {
            int lr = crd[k] >> 8, lc = crd[k] & 255;
            if ((flg[k] & 2) && lr > t && lr < S - t - 1 && lc > t && lc < S - t - 1) {
                int l = tid + k * NT;
                float wv = sw[l];
                float dh = (flg[k] & 4) ? sw[l + S] - wv : 0.f;
                float dw = (flg[k] & 8) ? sw[l + 1] - wv : 0.f;
                float u0v = su0[l], u1v = su1[l];
                float v0 = fmaf(SIGMA, dh, u0v);
                float v1 = fmaf(SIGMA, dw, u1v);
                float mag = sqrtf(fmaf(v0, v0, v1 * v1));
                float inv = 1.0f / fmaxf(mag * INV_THS, 1.0f);
                su0[l] = fmaf(RHO, v0 * inv - u0v, u0v);
                su1[l] = fmaf(RHO, v1 * inv - u1v, u1v);
                x2r[k] = fmaf(0.5f * RHO, wv - x2r[k], x2r[k]); // x2 + RHO*(x-x2)
            }
        }
        __syncthreads();
    }

    // ---- store central 64x64 from owned cells (x2 from reg, u from LDS)
    #pragma unroll
    for (int k = 0; k < NK; ++k) {
        if (flg[k] & 16) {
            int l = tid + k * NT;
            int lr = crd[k] >> 8, lc = crd[k] & 255;
            int gr = r0 + lr - KF, gc = c0 + lc - KF;
            size_t gi = plane + (size_t)gr * Ww + gc;
            x2_out[gi] = x2r[k];
            u0_out[gi] = su0[l];
            u1_out[gi] = su1[l];
        }
    }
}

extern "C" void kernel_launch(void* const* d_in, const int* in_sizes, int n_in,
                              void* d_out, int out_size, void* d_ws, size_t ws_size,
                              hipStream_t stream)
{
    const float* y = (const float*)d_in[0];
    float* out = (float*)d_out;
    const size_t NP = (size_t)Bb * Hh * Ww;   // 2M elements

    float* ws  = (float*)d_ws;
    float* x2A = ws;
    float* x2B = ws + NP;
    float* u0B = ws + 2 * NP;   // zeroed, read at launch 0
    float* u1B = ws + 3 * NP;   // zeroed (contiguous with u0B)
    float* u0A = ws + 4 * NP;
    float* u1A = ws + 5 * NP;
    // total ws use: 6*NP*4 = 48 MB

    hipMemsetAsync(u0B, 0, 2 * NP * sizeof(float), stream);

    dim3 grid(Ww / TS, Hh / TS, Bb);   // 8 x 8 x 8 = 512 blocks

    const float* x2r = y;       // x2_0 = y
    const float* u0r = u0B;
    const float* u1r = u1B;
    for (int i = 0; i < 5; ++i) {
        bool even = (i & 1) == 0;
        float* x2w = (i == 4) ? out : (even ? x2A : x2B);
        float* u0w = even ? u0A : u0B;
        float* u1w = even ? u1A : u1B;
        tv_fused<<<grid, NT, 0, stream>>>(x2r, u0r, u1r, y, x2w, u0w, u1w);
        x2r = x2w; u0r = u0w; u1r = u1w;
    }
}

// Round 6
// 285.030 us; speedup vs baseline: 3.4916x; 1.2450x over previous
//
#include <hip/hip_runtime.h>

// TV denoiser (Chambolle-Pock), 40 iterations = 5 launches x 8 fused steps.
// Temporal blocking on an 80x80 staged region -> central 64x64 output.
//
// 640 threads = 8 rows of 80: thread (lr0,lc) owns cells (lr0+8k, lc), k=0..9.
// lc is a thread constant; LDS addresses are base + 2560*k immediates.
// u0/u1 interleaved as float2 (LDS and global ws) -> b64 LDS ops, 8B global.
// Region masks as thresholds: phase1 active iff t < tm1 = min(lr,S-lr,lc,S-lc);
// phase2 iff t < tm2 = img ? min(lr,S-1-lr,lc,S-1-lc) : 0. Identical regions to
// the verified round-5 kernel. OOB cells never updated (round-2 invariant:
// drifting OOB u feeds back through the adjoint -> fail).
// Projection via rsqrt: u = v * min(THS * rsqrt(|v|^2), 1)  (mag2=0 -> inf -> 1).

#define Hh 512
#define Ww 512
#define Bb 8
#define TS 64
#define KF 8
#define S  80
#define SS (S*S)       // 6400
#define NT 640
#define NK 10

__global__ __launch_bounds__(NT, 5)
void tv_fused(const float*  __restrict__ x2_in,
              const float2* __restrict__ u_in,
              const float*  __restrict__ y_in,
              float*  __restrict__ x2_out,
              float2* __restrict__ u_out)
{
    constexpr float TAU = 0.01f;
    constexpr float RHO = 1.99f;
    constexpr float SIGMA = 12.5f;       // 1/TAU/8
    constexpr float THS = 0.1f;
    constexpr float INV_1PT = 1.0f / 1.01f;

    __shared__ float2 su[SS];            // 51.2 KB
    __shared__ float  sw[SS];            // 25.6 KB

    const int b   = blockIdx.z;
    const int r0  = blockIdx.y * TS;
    const int c0  = blockIdx.x * TS;
    const int tid = threadIdx.x;
    const size_t plane = (size_t)b * (Hh * Ww);

    const int lr0 = tid / S;             // 0..7
    const int lc  = tid - lr0 * S;       // 0..79
    const int gc  = c0 - KF + lc;
    const bool cok = (gc >= 0) & (gc < Ww);
    const float ewf = (gc < Ww - 1) ? 1.f : 0.f;

    float x2r[NK], yr[NK], ehf[NK];
    int   tm1[NK], tm2[NK];

    // ---- stage
    #pragma unroll
    for (int k = 0; k < NK; ++k) {
        int lr = lr0 + 8 * k;
        int gr = r0 - KF + lr;
        int l  = tid + NT * k;
        bool img = cok & (gr >= 0) & (gr < Hh);
        float a = 0.f, c = 0.f;
        float2 uu = make_float2(0.f, 0.f);
        if (img) {
            size_t gi = plane + (size_t)gr * Ww + gc;
            a  = x2_in[gi];
            uu = u_in [gi];
            c  = y_in [gi];
        }
        x2r[k] = a; yr[k] = c;
        su[l] = uu;
        ehf[k] = (gr < Hh - 1) ? 1.f : 0.f;
        int m1 = min(min(lr, S - lr), min(lc, S - lc));
        int m2 = min(min(lr, S - 1 - lr), min(lc, S - 1 - lc));
        tm1[k] = m1;
        tm2[k] = img ? m2 : 0;
    }
    __syncthreads();

    for (int t = 0; t < KF; ++t) {
        // ---- phase 1: w = 2x - x2
        #pragma unroll
        for (int k = 0; k < NK; ++k) {
            if (t < tm1[k]) {
                int l = tid + NT * k;
                float2 uc = su[l];
                float adj = su[l - S].x - uc.x + su[l - 1].y - uc.y;
                float tmp = fmaf(TAU, yr[k] - adj, x2r[k]);     // x*(1+TAU)
                sw[l] = fmaf(2.0f * INV_1PT, tmp, -x2r[k]);     // 2x - x2
            }
        }
        __syncthreads();
        // ---- phase 2: u, x2 update
        #pragma unroll
        for (int k = 0; k < NK; ++k) {
            if (t < tm2[k]) {
                int l = tid + NT * k;
                float wv = sw[l];
                float dh = ehf[k] * (sw[l + S] - wv);
                float dw = ewf    * (sw[l + 1] - wv);
                float2 uc = su[l];
                float v0 = fmaf(SIGMA, dh, uc.x);
                float v1 = fmaf(SIGMA, dw, uc.y);
                float mag2 = fmaf(v0, v0, v1 * v1);
                float inv = fminf(THS * __builtin_amdgcn_rsqf(mag2), 1.f);
                su[l] = make_float2(fmaf(RHO, v0 * inv - uc.x, uc.x),
                                    fmaf(RHO, v1 * inv - uc.y, uc.y));
                x2r[k] = fmaf(0.5f * RHO, wv - x2r[k], x2r[k]); // x2 + RHO*(x-x2)
            }
        }
        __syncthreads();
    }

    // ---- store central 64x64: rows are k=1..8 for every thread; cols lc in [8,72)
    if (cok & (lc >= KF) & (lc < KF + TS)) {
        #pragma unroll
        for (int k = 1; k <= 8; ++k) {
            int lr = lr0 + 8 * k;
            int l  = tid + NT * k;
            size_t gi = plane + (size_t)(r0 + lr - KF) * Ww + (c0 + lc - KF);
            x2_out[gi] = x2r[k];
            u_out [gi] = su[l];
        }
    }
}

extern "C" void kernel_launch(void* const* d_in, const int* in_sizes, int n_in,
                              void* d_out, int out_size, void* d_ws, size_t ws_size,
                              hipStream_t stream)
{
    const float* y = (const float*)d_in[0];
    float* out = (float*)d_out;
    const size_t NP = (size_t)Bb * Hh * Ww;   // 2M elements

    float*  ws  = (float*)d_ws;
    float*  x2A = ws;                          // 8 MB
    float*  x2B = ws + NP;                     // 8 MB
    float2* uB  = (float2*)(ws + 2 * NP);      // 16 MB (zeroed, read at launch 0)
    float2* uA  = (float2*)(ws + 4 * NP);      // 16 MB
    // total ws use: 6*NP*4 = 48 MB

    hipMemsetAsync(uB, 0, 2 * NP * sizeof(float), stream);

    dim3 grid(Ww / TS, Hh / TS, Bb);   // 8 x 8 x 8 = 512 blocks

    const float*  x2r = y;      // x2_0 = y
    const float2* ur  = uB;
    for (int i = 0; i < 5; ++i) {
        bool even = (i & 1) == 0;
        float*  x2w = (i == 4) ? out : (even ? x2A : x2B);
        float2* uw  = even ? uA : uB;
        tv_fused<<<grid, NT, 0, stream>>>(x2r, ur, y, x2w, uw);
        x2r = x2w; ur = uw;
    }
}

// Round 7
// 278.047 us; speedup vs baseline: 3.5793x; 1.0251x over previous
//
#include <hip/hip_runtime.h>

// TV denoiser (Chambolle-Pock), 40 iterations = 5 launches x 8 fused steps.
// Temporal blocking on an 80x80 staged region -> central 64x64 output.
//
// 640 threads = 8 rows of 80: thread (lr0,lc) owns cells (lr0+8k, lc), k=0..9.
// lc is a thread constant; LDS addresses are base + 2560*k immediates.
//
// LDS layout lesson (round 6): float2-interleaved su caused 2.94M bank
// conflicts/dispatch (scalar .x/.y reads at 8B stride hit only even/odd banks
// -> 4-way conflict). su0/su1 are SEPARATE stride-1 float arrays; global u
// stays float2-interleaved (coalesced 8B, banks don't apply to HBM).
//
// Region masks as thresholds: phase1 active iff t < tm1 = min(lr,S-lr,lc,S-lc);
// phase2 iff t < tm2 = img ? min(lr,S-1-lr,lc,S-1-lc) : 0. OOB cells are never
// updated (round-2 invariant: drifting OOB u feeds back through the adjoint).
// Projection via rsqrt: u = v * min(THS * rsqrt(|v|^2), 1)  (mag2=0 -> inf -> 1).

#define Hh 512
#define Ww 512
#define Bb 8
#define TS 64
#define KF 8
#define S  80
#define SS (S*S)       // 6400
#define NT 640
#define NK 10

__global__ __launch_bounds__(NT, 5)
void tv_fused(const float*  __restrict__ x2_in,
              const float2* __restrict__ u_in,
              const float*  __restrict__ y_in,
              float*  __restrict__ x2_out,
              float2* __restrict__ u_out)
{
    constexpr float TAU = 0.01f;
    constexpr float RHO = 1.99f;
    constexpr float SIGMA = 12.5f;       // 1/TAU/8
    constexpr float THS = 0.1f;
    constexpr float INV_1PT = 1.0f / 1.01f;

    __shared__ float su0[SS];            // 25.6 KB
    __shared__ float su1[SS];            // 25.6 KB
    __shared__ float sw [SS];            // 25.6 KB

    const int b   = blockIdx.z;
    const int r0  = blockIdx.y * TS;
    const int c0  = blockIdx.x * TS;
    const int tid = threadIdx.x;
    const size_t plane = (size_t)b * (Hh * Ww);

    const int lr0 = tid / S;             // 0..7
    const int lc  = tid - lr0 * S;       // 0..79
    const int gc  = c0 - KF + lc;
    const bool cok = (gc >= 0) & (gc < Ww);
    const float ewf = (gc < Ww - 1) ? 1.f : 0.f;

    float x2r[NK], yr[NK], ehf[NK];
    int   tm1[NK], tm2[NK];

    // ---- stage
    #pragma unroll
    for (int k = 0; k < NK; ++k) {
        int lr = lr0 + 8 * k;
        int gr = r0 - KF + lr;
        int l  = tid + NT * k;
        bool img = cok & (gr >= 0) & (gr < Hh);
        float a = 0.f, c = 0.f;
        float2 uu = make_float2(0.f, 0.f);
        if (img) {
            size_t gi = plane + (size_t)gr * Ww + gc;
            a  = x2_in[gi];
            uu = u_in [gi];
            c  = y_in [gi];
        }
        x2r[k] = a; yr[k] = c;
        su0[l] = uu.x;
        su1[l] = uu.y;
        ehf[k] = (gr < Hh - 1) ? 1.f : 0.f;
        int m1 = min(min(lr, S - lr), min(lc, S - lc));
        int m2 = min(min(lr, S - 1 - lr), min(lc, S - 1 - lc));
        tm1[k] = m1;
        tm2[k] = img ? m2 : 0;
    }
    __syncthreads();

    for (int t = 0; t < KF; ++t) {
        // ---- phase 1: w = 2x - x2
        #pragma unroll
        for (int k = 0; k < NK; ++k) {
            if (t < tm1[k]) {
                int l = tid + NT * k;
                float adj = su0[l - S] - su0[l] + su1[l - 1] - su1[l];
                float tmp = fmaf(TAU, yr[k] - adj, x2r[k]);     // x*(1+TAU)
                sw[l] = fmaf(2.0f * INV_1PT, tmp, -x2r[k]);     // 2x - x2
            }
        }
        __syncthreads();
        // ---- phase 2: u, x2 update
        #pragma unroll
        for (int k = 0; k < NK; ++k) {
            if (t < tm2[k]) {
                int l = tid + NT * k;
                float wv = sw[l];
                float dh = ehf[k] * (sw[l + S] - wv);
                float dw = ewf    * (sw[l + 1] - wv);
                float u0v = su0[l], u1v = su1[l];
                float v0 = fmaf(SIGMA, dh, u0v);
                float v1 = fmaf(SIGMA, dw, u1v);
                float mag2 = fmaf(v0, v0, v1 * v1);
                float inv = fminf(THS * __builtin_amdgcn_rsqf(mag2), 1.f);
                su0[l] = fmaf(RHO, v0 * inv - u0v, u0v);
                su1[l] = fmaf(RHO, v1 * inv - u1v, u1v);
                x2r[k] = fmaf(0.5f * RHO, wv - x2r[k], x2r[k]); // x2 + RHO*(x-x2)
            }
        }
        __syncthreads();
    }

    // ---- store central 64x64: rows are k=1..8 for every thread; cols lc in [8,72)
    if (cok & (lc >= KF) & (lc < KF + TS)) {
        #pragma unroll
        for (int k = 1; k <= 8; ++k) {
            int lr = lr0 + 8 * k;
            int l  = tid + NT * k;
            size_t gi = plane + (size_t)(r0 + lr - KF) * Ww + (c0 + lc - KF);
            x2_out[gi] = x2r[k];
            u_out [gi] = make_float2(su0[l], su1[l]);
        }
    }
}

extern "C" void kernel_launch(void* const* d_in, const int* in_sizes, int n_in,
                              void* d_out, int out_size, void* d_ws, size_t ws_size,
                              hipStream_t stream)
{
    const float* y = (const float*)d_in[0];
    float* out = (float*)d_out;
    const size_t NP = (size_t)Bb * Hh * Ww;   // 2M elements

    float*  ws  = (float*)d_ws;
    float*  x2A = ws;                          // 8 MB
    float*  x2B = ws + NP;                     // 8 MB
    float2* uB  = (float2*)(ws + 2 * NP);      // 16 MB (zeroed, read at launch 0)
    float2* uA  = (float2*)(ws + 4 * NP);      // 16 MB
    // total ws use: 6*NP*4 = 48 MB

    hipMemsetAsync(uB, 0, 2 * NP * sizeof(float), stream);

    dim3 grid(Ww / TS, Hh / TS, Bb);   // 8 x 8 x 8 = 512 blocks

    const float*  x2r = y;      // x2_0 = y
    const float2* ur  = uB;
    for (int i = 0; i < 5; ++i) {
        bool even = (i & 1) == 0;
        float*  x2w = (i == 4) ? out : (even ? x2A : x2B);
        float2* uw  = even ? uA : uB;
        tv_fused<<<grid, NT, 0, stream>>>(x2r, ur, y, x2w, uw);
        x2r = x2w; ur = uw;
    }
}